// Round 6
// baseline (1188.451 us; speedup 1.0000x reference)
//
#include <hip/hip_runtime.h>
#include <hip/hip_bf16.h>

// ---------------------------------------------------------------------------
// MCT tracklet-affinity pipeline. fp32 in/out, bf16 MFMA internally.
//   g    = f - relu(f @ Wc1^T + bc1)             [192,4096] fp32 in ws
//   dist = |g_i - g_j| for upper-tri rows        [R,4096] bf16, materialized
//   h1   = relu(dist @ W1^T + b1)                [R,2048] bf16
//   h2   = relu(h1 @ W2^T + b2)                  [R,1024]
//   h3   = relu(h2 @ W3^T + b3)                  [R,512]
//   A[i,j]=A[j,i]=sigmoid(h3 . Ws + bs)          [192,192] fp32
// Round-6: MLP GEMMs use v_mfma_f32_32x32x16_bf16 (16 MFMA@8cyc vs 32@4.85
// per BK=64 iter = -17% matrix cycles; frag VGPRs 32->16 -> target 64+64acc
// = 4 waves/SIMD vs 3). C/D layout per m74/m101: col=lane&31,
// row=(reg&3)+8*(reg>>2)+4*(lane>>5). A/B: [dim=lane&31][k=(lane>>5)*8+j].
// Grid: x = column tile (fast) for XCD L2 W-residency (round-5 win).
// ---------------------------------------------------------------------------

typedef unsigned short u16;
typedef __attribute__((ext_vector_type(8)))  short    bf16x8;
typedef __attribute__((ext_vector_type(8)))  unsigned short u16x8;
typedef __attribute__((ext_vector_type(4)))  float    f32x4;
typedef __attribute__((ext_vector_type(16))) float    f32x16;

#define MFMA16(a, b, c) __builtin_amdgcn_mfma_f32_16x16x32_bf16((a), (b), (c), 0, 0, 0)
#define MFMA32(a, b, c) __builtin_amdgcn_mfma_f32_32x32x16_bf16((a), (b), (c), 0, 0, 0)

#define NTRK 192
#define TRI  18528         /* 192*193/2 upper-tri rows incl diagonal */
#define TRIP 18688         /* padded to 146*128 */

__device__ __forceinline__ unsigned int pkbf(float lo, float hi) {
    __hip_bfloat162 h2 = __float22bfloat162_rn(make_float2(lo, hi));
    return *reinterpret_cast<unsigned int*>(&h2);
}
__device__ __forceinline__ void gll16(void* lds_uniform, const void* gsrc) {
    __builtin_amdgcn_global_load_lds(
        (__attribute__((address_space(1))) void*)(gsrc),
        (__attribute__((address_space(3))) void*)(lds_uniform),
        16, 0, 0);
}
// triangle row r -> (i,j), i<=j. T(i) = i*(385-i)/2. Clamped for padding rows.
__device__ __forceinline__ void tri_decode(int r, int& oi, int& oj) {
    double a = 192.5;
    int i = (int)(a - sqrt(a * a - 2.0 * (double)r));
    i = i < 0 ? 0 : (i > 191 ? 191 : i);
    while (i < 191 && (i + 1) * (385 - (i + 1)) / 2 <= r) ++i;
    while (i > 0 && i * (385 - i) / 2 > r) --i;
    int j = i + (r - i * (385 - i) / 2);
    oi = i; oj = j > 191 ? 191 : j;
}

// ---------------------------------------------------------------------------
__global__ __launch_bounds__(256)
void k_cvt(const float* __restrict__ src, u16* __restrict__ dst, int n4)
{
    int i = blockIdx.x * blockDim.x + threadIdx.x;
    const int stride = gridDim.x * blockDim.x;
    for (; i < n4; i += stride) {
        f32x4 v = ((const f32x4*)src)[i];
        ((uint2*)dst)[i] = make_uint2(pkbf(v.x, v.y), pkbf(v.z, v.w));
    }
}

// ---------------------------------------------------------------------------
// g = f - relu(fb @ Wc1b^T + bc1).  M=192,N=4096,K=4096. BM=64,BN=128,BK=64.
// (16x16x32 MFMA; small kernel, proven — left unchanged.)
// ---------------------------------------------------------------------------
__global__ __launch_bounds__(256, 2)
void k_cam(const u16* __restrict__ fb, const u16* __restrict__ Wc1b,
           const float* __restrict__ bc1, const float* __restrict__ f,
           float* __restrict__ gout)
{
    __shared__ __align__(16) u16 As[64 * 64];
    __shared__ __align__(16) u16 Bs[128 * 64];
    const int t = threadIdx.x, l = t & 63, w = t >> 6;
    const int m0 = blockIdx.x * 64, n0 = blockIdx.y * 128;
    const u16* Ab = fb   + (size_t)(m0 + w * 16 + (l >> 3)) * 4096 + (l & 7) * 8;
    const u16* Bb = Wc1b + (size_t)(n0 + w * 32 + (l >> 3)) * 4096 + (l & 7) * 8;
    f32x4 acc[2][4] = {};
    const int wr = (w >> 1) * 32, wc = (w & 1) * 64;
    const int lrow = l & 15, lk = (l >> 4) * 8;

    for (int k0 = 0; k0 < 4096; k0 += 64) {
        __syncthreads();
#pragma unroll
        for (int q = 0; q < 2; ++q)
            gll16(&As[(w * 16 + q * 8) * 64], Ab + (size_t)q * 8 * 4096 + k0);
#pragma unroll
        for (int q = 0; q < 4; ++q)
            gll16(&Bs[(w * 32 + q * 8) * 64], Bb + (size_t)q * 8 * 4096 + k0);
        __syncthreads();
#pragma unroll
        for (int kk = 0; kk < 64; kk += 32) {
            bf16x8 af[2], bfr[4];
#pragma unroll
            for (int mi = 0; mi < 2; ++mi)
                af[mi] = *(const bf16x8*)&As[(wr + mi * 16 + lrow) * 64 + kk + lk];
#pragma unroll
            for (int ni = 0; ni < 4; ++ni)
                bfr[ni] = *(const bf16x8*)&Bs[(wc + ni * 16 + lrow) * 64 + kk + lk];
#pragma unroll
            for (int mi = 0; mi < 2; ++mi)
#pragma unroll
                for (int ni = 0; ni < 4; ++ni)
                    acc[mi][ni] = MFMA16(af[mi], bfr[ni], acc[mi][ni]);
        }
    }
    const int rq = (l >> 4) * 4;
#pragma unroll
    for (int ni = 0; ni < 4; ++ni) {
        const int col = n0 + wc + ni * 16 + lrow;
        const float bias = bc1[col];
#pragma unroll
        for (int mi = 0; mi < 2; ++mi) {
            const int rbase = m0 + wr + mi * 16 + rq;
#pragma unroll
            for (int v = 0; v < 4; ++v) {
                const int row = rbase + v;
                float cam = fmaxf(acc[mi][ni][v] + bias, 0.0f);
                gout[(size_t)row * 4096 + col] = f[(size_t)row * 4096 + col] - cam;
            }
        }
    }
}

// ---------------------------------------------------------------------------
// dist[r, :] = bf16(|g_i - g_j|). One 16B chunk per thread. grid (2, rows).
// ---------------------------------------------------------------------------
__global__ __launch_bounds__(256)
void k_distgen(const float* __restrict__ g, u16* __restrict__ dist, int row0)
{
    const int r = blockIdx.y;
    const int c = blockIdx.x * 256 + threadIdx.x;       // chunk 0..511
    int pi, pj; tri_decode(row0 + r, pi, pj);
    const float* gi = g + (size_t)pi * 4096 + c * 8;
    const float* gj = g + (size_t)pj * 4096 + c * 8;
    f32x4 a0 = ((const f32x4*)gi)[0], a1 = ((const f32x4*)gi)[1];
    f32x4 b0 = ((const f32x4*)gj)[0], b1 = ((const f32x4*)gj)[1];
    uint4 o;
    o.x = pkbf(fabsf(b0.x - a0.x), fabsf(b0.y - a0.y));
    o.y = pkbf(fabsf(b0.z - a0.z), fabsf(b0.w - a0.w));
    o.z = pkbf(fabsf(b1.x - a1.x), fabsf(b1.y - a1.y));
    o.w = pkbf(fabsf(b1.z - a1.z), fabsf(b1.w - a1.w));
    *reinterpret_cast<uint4*>(dist + (size_t)r * 4096 + c * 8) = o;
}

// ---------------------------------------------------------------------------
// C = relu(A @ B^T + bias), bf16, 32x32x16 MFMA. BM=BN=128, BK=64, 256 thr,
// wave tile 64x64 = 2x2 of 32x32. grid (N/128, M/128): x = COLUMN tile.
// Frag: A[m=lane&31][k=(lane>>5)*8+j] read as one b128; B symmetric.
// C/D: col=lane&31, row=(reg&3)+8*(reg>>2)+4*(lane>>5)  [m74/m101 verified].
// ---------------------------------------------------------------------------
__global__ __launch_bounds__(256, 2)
void k_gemm_relu(const u16* __restrict__ A, const u16* __restrict__ B,
                 const float* __restrict__ bias, u16* __restrict__ C,
                 int N, int K)
{
    __shared__ __align__(16) u16 As[128 * 64];
    __shared__ __align__(16) u16 Bs[128 * 64];
    const int t = threadIdx.x, l = t & 63, w = t >> 6;
    const int m0 = blockIdx.y * 128, n0 = blockIdx.x * 128;   // x = column!
    const u16* Ab = A + (size_t)(m0 + w * 32 + (l >> 3)) * K + (l & 7) * 8;
    const u16* Bb = B + (size_t)(n0 + w * 32 + (l >> 3)) * K + (l & 7) * 8;
    f32x16 acc[2][2] = {};
    const int wr = (w >> 1) * 64, wc = (w & 1) * 64;
    const int lm = l & 31;        // row/col within 32-tile
    const int lh = l >> 5;        // k-half selector
    const int lko = lh * 8;

    for (int k0 = 0; k0 < K; k0 += 64) {
        __syncthreads();
#pragma unroll
        for (int q = 0; q < 4; ++q) {
            gll16(&As[(w * 32 + q * 8) * 64], Ab + (size_t)q * 8 * K + k0);
            gll16(&Bs[(w * 32 + q * 8) * 64], Bb + (size_t)q * 8 * K + k0);
        }
        __syncthreads();
#pragma unroll
        for (int kk = 0; kk < 64; kk += 16) {
            bf16x8 af[2], bfr[2];
#pragma unroll
            for (int mi = 0; mi < 2; ++mi)
                af[mi] = *(const bf16x8*)&As[(wr + mi * 32 + lm) * 64 + kk + lko];
#pragma unroll
            for (int ni = 0; ni < 2; ++ni)
                bfr[ni] = *(const bf16x8*)&Bs[(wc + ni * 32 + lm) * 64 + kk + lko];
#pragma unroll
            for (int mi = 0; mi < 2; ++mi)
#pragma unroll
                for (int ni = 0; ni < 2; ++ni)
                    acc[mi][ni] = MFMA32(af[mi], bfr[ni], acc[mi][ni]);
        }
    }
#pragma unroll
    for (int ni = 0; ni < 2; ++ni) {
        const int col = n0 + wc + ni * 32 + lm;
        const float bv = bias[col];
#pragma unroll
        for (int mi = 0; mi < 2; ++mi) {
            const int rbase = m0 + wr + mi * 32 + 4 * lh;
#pragma unroll
            for (int r = 0; r < 16; ++r) {
                const int row = rbase + (r & 3) + 8 * (r >> 2);
                float x = fmaxf(acc[mi][ni][r] + bv, 0.0f);
                C[(size_t)row * N + col] = (u16)(pkbf(x, 0.0f) & 0xFFFF);
            }
        }
    }
}

// ---------------------------------------------------------------------------
// out[i,j] = out[j,i] = sigmoid(h3[r,:512] . Ws + bs). One wave per tri-row.
// ---------------------------------------------------------------------------
__global__ __launch_bounds__(256)
void k_head(const u16* __restrict__ h3, const float* __restrict__ Wsv,
            const float* __restrict__ bsv, float* __restrict__ out, int row0)
{
    const int t = threadIdx.x, l = t & 63, wv = t >> 6;
    const int rl = blockIdx.x * 4 + wv;
    if (row0 + rl >= TRI) return;
    const u16x8 hv = *(const u16x8*)(h3 + (size_t)rl * 512 + l * 8);
    const f32x4 w0 = ((const f32x4*)Wsv)[l * 2];
    const f32x4 w1 = ((const f32x4*)Wsv)[l * 2 + 1];
    float hs[8];
#pragma unroll
    for (int e = 0; e < 8; ++e) {
        union { unsigned int i; float f; } v;
        v.i = ((unsigned int)hv[e]) << 16;
        hs[e] = v.f;
    }
    float s = hs[0] * w0.x + hs[1] * w0.y + hs[2] * w0.z + hs[3] * w0.w
            + hs[4] * w1.x + hs[5] * w1.y + hs[6] * w1.z + hs[7] * w1.w;
#pragma unroll
    for (int off = 32; off >= 1; off >>= 1) s += __shfl_down(s, off, 64);
    if (l == 0) {
        float v = 1.0f / (1.0f + __expf(-(s + bsv[0])));
        int pi, pj; tri_decode(row0 + rl, pi, pj);
        out[pi * NTRK + pj] = v;
        out[pj * NTRK + pi] = v;
    }
}

// ---------------------------------------------------------------------------
extern "C" void kernel_launch(void* const* d_in, const int* in_sizes, int n_in,
                              void* d_out, int out_size, void* d_ws, size_t ws_size,
                              hipStream_t stream)
{
    const float* f   = (const float*)d_in[0];
    const float* Wc1 = (const float*)d_in[1];
    const float* bc1 = (const float*)d_in[2];
    const float* W1  = (const float*)d_in[3];
    const float* b1  = (const float*)d_in[4];
    const float* W2  = (const float*)d_in[5];
    const float* b2  = (const float*)d_in[6];
    const float* W3  = (const float*)d_in[7];
    const float* b3  = (const float*)d_in[8];
    const float* Wsv = (const float*)d_in[9];
    const float* bsv = (const float*)d_in[10];
    float* out = (float*)d_out;

    char* wsb = (char*)d_ws;
    size_t off = 0;
    u16* Wc1b = (u16*)(wsb + off); off += (size_t)4096 * 4096 * 2;
    u16* W1b  = (u16*)(wsb + off); off += (size_t)2048 * 4096 * 2;
    u16* W2b  = (u16*)(wsb + off); off += (size_t)1024 * 2048 * 2;
    u16* W3b  = (u16*)(wsb + off); off += (size_t)512  * 1024 * 2;
    u16* fb   = (u16*)(wsb + off); off += (size_t)192  * 4096 * 2;
    float* g  = (float*)(wsb + off); off += (size_t)192 * 4096 * 4;
    const size_t fixed = off;

    // chunk rows (mult of 128): need dist + h1 + h2 + h3 = R*15360 bytes
    const int Rcand[6] = {18688, 9344, 4736, 2432, 1280, 384};
    int R = 128;
    for (int c = 0; c < 6; ++c) {
        size_t need = fixed + (size_t)Rcand[c] * 15360;
        if (need <= ws_size) { R = Rcand[c]; break; }
    }
    u16* dist = (u16*)(wsb + fixed);
    u16* h1 = dist + (size_t)R * 4096;
    u16* h2 = h1 + (size_t)R * 2048;
    u16* h3 = h2 + (size_t)R * 1024;

    k_cvt<<<512, 256, 0, stream>>>(Wc1, Wc1b, 4096 * 4096 / 4);
    k_cvt<<<512, 256, 0, stream>>>(W1,  W1b,  2048 * 4096 / 4);
    k_cvt<<<256, 256, 0, stream>>>(W2,  W2b,  1024 * 2048 / 4);
    k_cvt<<<128, 256, 0, stream>>>(W3,  W3b,  512  * 1024 / 4);
    k_cvt<<<128, 256, 0, stream>>>(f,   fb,   192  * 4096 / 4);

    k_cam<<<dim3(3, 32), 256, 0, stream>>>(fb, Wc1b, bc1, f, g);

    for (int r0 = 0; r0 < TRI; r0 += R) {
        int rows = TRIP - r0; if (rows > R) rows = R;   // mult of 128
        k_distgen<<<dim3(2, rows), 256, 0, stream>>>(g, dist, r0);
        k_gemm_relu<<<dim3(16, rows / 128), 256, 0, stream>>>(dist, W1b, b1, h1, 2048, 4096);
        k_gemm_relu<<<dim3(8,  rows / 128), 256, 0, stream>>>(h1, W2b, b2, h2, 1024, 2048);
        k_gemm_relu<<<dim3(4,  rows / 128), 256, 0, stream>>>(h2, W3b, b3, h3, 512, 1024);
        k_head<<<dim3(rows / 4), 256, 0, stream>>>(h3, Wsv, bsv, out, r0);
    }
}

// Round 7
// 748.612 us; speedup vs baseline: 1.5875x; 1.5875x over previous
//
#include <hip/hip_runtime.h>
#include <hip/hip_bf16.h>

// ---------------------------------------------------------------------------
// MCT tracklet-affinity pipeline. fp32 in/out, bf16 MFMA internally.
//   g    = f - relu(f @ Wc1^T + bc1)             [192,4096] fp32 in ws
//   dist = |g_i - g_j| for upper-tri rows        [R,4096] bf16, materialized
//   h1   = relu(dist @ W1^T + b1)                [R,2048] bf16
//   h2   = relu(h1 @ W2^T + b2)                  [R,1024]
//   h3   = relu(h2 @ W3^T + b3)                  [R,512]
//   A[i,j]=A[j,i]=sigmoid(h3 . Ws + bs)          [192,192] fp32
// Round-7: back to 16x16x32 MFMA (round-6's 32x32 doubled bank conflicts:
// row stride 128B = 0 mod 32 banks, 32 lanes on one 4-bank group).
// NEW: XOR swizzle in LDS staging — lane l stages global chunk (l&7)^(l>>3)
// (gll16-compatible: same 1024B wave footprint, lanes permuted); fragment
// reads use chunk cg^(row&7). Rows 0-7 then cover all 32 banks (2-way for
// 16 rows = free per m136) instead of 16-way on one group.
// Grid: x = column tile (fast) for XCD L2 W-residency (round-5 win).
// ---------------------------------------------------------------------------

typedef unsigned short u16;
typedef __attribute__((ext_vector_type(8))) short    bf16x8;
typedef __attribute__((ext_vector_type(8))) unsigned short u16x8;
typedef __attribute__((ext_vector_type(4))) float    f32x4;

#define MFMA16(a, b, c) __builtin_amdgcn_mfma_f32_16x16x32_bf16((a), (b), (c), 0, 0, 0)

#define NTRK 192
#define TRI  18528         /* 192*193/2 upper-tri rows incl diagonal */
#define TRIP 18688         /* padded to 146*128 */

__device__ __forceinline__ unsigned int pkbf(float lo, float hi) {
    __hip_bfloat162 h2 = __float22bfloat162_rn(make_float2(lo, hi));
    return *reinterpret_cast<unsigned int*>(&h2);
}
__device__ __forceinline__ void gll16(void* lds_uniform, const void* gsrc) {
    __builtin_amdgcn_global_load_lds(
        (__attribute__((address_space(1))) void*)(gsrc),
        (__attribute__((address_space(3))) void*)(lds_uniform),
        16, 0, 0);
}
// triangle row r -> (i,j), i<=j. T(i) = i*(385-i)/2. Clamped for padding rows.
__device__ __forceinline__ void tri_decode(int r, int& oi, int& oj) {
    double a = 192.5;
    int i = (int)(a - sqrt(a * a - 2.0 * (double)r));
    i = i < 0 ? 0 : (i > 191 ? 191 : i);
    while (i < 191 && (i + 1) * (385 - (i + 1)) / 2 <= r) ++i;
    while (i > 0 && i * (385 - i) / 2 > r) --i;
    int j = i + (r - i * (385 - i) / 2);
    oi = i; oj = j > 191 ? 191 : j;
}

// ---------------------------------------------------------------------------
__global__ __launch_bounds__(256)
void k_cvt(const float* __restrict__ src, u16* __restrict__ dst, int n4)
{
    int i = blockIdx.x * blockDim.x + threadIdx.x;
    const int stride = gridDim.x * blockDim.x;
    for (; i < n4; i += stride) {
        f32x4 v = ((const f32x4*)src)[i];
        ((uint2*)dst)[i] = make_uint2(pkbf(v.x, v.y), pkbf(v.z, v.w));
    }
}

// ---------------------------------------------------------------------------
// g = f - relu(fb @ Wc1b^T + bc1).  M=192,N=4096,K=4096. BM=64,BN=128,BK=64.
// Same XOR-swizzled staging/reads as k_gemm_relu.
// ---------------------------------------------------------------------------
__global__ __launch_bounds__(256, 2)
void k_cam(const u16* __restrict__ fb, const u16* __restrict__ Wc1b,
           const float* __restrict__ bc1, const float* __restrict__ f,
           float* __restrict__ gout)
{
    __shared__ __align__(16) u16 As[64 * 64];
    __shared__ __align__(16) u16 Bs[128 * 64];
    const int t = threadIdx.x, l = t & 63, w = t >> 6;
    const int m0 = blockIdx.x * 64, n0 = blockIdx.y * 128;
    const int lr8 = l >> 3;                 // row within 8-row staging chunk
    const int lc8 = (l & 7) ^ lr8;          // swizzled 16B chunk to fetch
    const u16* Ab = fb   + (size_t)(m0 + w * 16 + lr8) * 4096 + lc8 * 8;
    const u16* Bb = Wc1b + (size_t)(n0 + w * 32 + lr8) * 4096 + lc8 * 8;
    f32x4 acc[2][4] = {};
    const int wr = (w >> 1) * 32, wc = (w & 1) * 64;
    const int lrow = l & 15, lq = l >> 4, s = lrow & 7;

    for (int k0 = 0; k0 < 4096; k0 += 64) {
        __syncthreads();
#pragma unroll
        for (int q = 0; q < 2; ++q)
            gll16(&As[(w * 16 + q * 8) * 64], Ab + (size_t)q * 8 * 4096 + k0);
#pragma unroll
        for (int q = 0; q < 4; ++q)
            gll16(&Bs[(w * 32 + q * 8) * 64], Bb + (size_t)q * 8 * 4096 + k0);
        __syncthreads();
#pragma unroll
        for (int kk8 = 0; kk8 < 8; kk8 += 4) {
            const int co = ((kk8 + lq) ^ s) * 8;
            bf16x8 af[2], bfr[4];
#pragma unroll
            for (int mi = 0; mi < 2; ++mi)
                af[mi] = *(const bf16x8*)&As[(wr + mi * 16 + lrow) * 64 + co];
#pragma unroll
            for (int ni = 0; ni < 4; ++ni)
                bfr[ni] = *(const bf16x8*)&Bs[(wc + ni * 16 + lrow) * 64 + co];
#pragma unroll
            for (int mi = 0; mi < 2; ++mi)
#pragma unroll
                for (int ni = 0; ni < 4; ++ni)
                    acc[mi][ni] = MFMA16(af[mi], bfr[ni], acc[mi][ni]);
        }
    }
    const int rq = (l >> 4) * 4;
#pragma unroll
    for (int ni = 0; ni < 4; ++ni) {
        const int col = n0 + wc + ni * 16 + lrow;
        const float bias = bc1[col];
#pragma unroll
        for (int mi = 0; mi < 2; ++mi) {
            const int rbase = m0 + wr + mi * 16 + rq;
#pragma unroll
            for (int v = 0; v < 4; ++v) {
                const int row = rbase + v;
                float cam = fmaxf(acc[mi][ni][v] + bias, 0.0f);
                gout[(size_t)row * 4096 + col] = f[(size_t)row * 4096 + col] - cam;
            }
        }
    }
}

// ---------------------------------------------------------------------------
// dist[r, :] = bf16(|g_i - g_j|). One 16B chunk per thread. grid (2, rows).
// ---------------------------------------------------------------------------
__global__ __launch_bounds__(256)
void k_distgen(const float* __restrict__ g, u16* __restrict__ dist, int row0)
{
    const int r = blockIdx.y;
    const int c = blockIdx.x * 256 + threadIdx.x;       // chunk 0..511
    int pi, pj; tri_decode(row0 + r, pi, pj);
    const float* gi = g + (size_t)pi * 4096 + c * 8;
    const float* gj = g + (size_t)pj * 4096 + c * 8;
    f32x4 a0 = ((const f32x4*)gi)[0], a1 = ((const f32x4*)gi)[1];
    f32x4 b0 = ((const f32x4*)gj)[0], b1 = ((const f32x4*)gj)[1];
    uint4 o;
    o.x = pkbf(fabsf(b0.x - a0.x), fabsf(b0.y - a0.y));
    o.y = pkbf(fabsf(b0.z - a0.z), fabsf(b0.w - a0.w));
    o.z = pkbf(fabsf(b1.x - a1.x), fabsf(b1.y - a1.y));
    o.w = pkbf(fabsf(b1.z - a1.z), fabsf(b1.w - a1.w));
    *reinterpret_cast<uint4*>(dist + (size_t)r * 4096 + c * 8) = o;
}

// ---------------------------------------------------------------------------
// C = relu(A @ B^T + bias), bf16, 16x16x32 MFMA. BM=BN=128, BK=64, 256 thr,
// wave tile 64x64. grid (N/128, M/128): x = COLUMN tile (fast).
// XOR-swizzled LDS: stage chunk (l&7)^(l>>3), read chunk (ck)^(row&7).
// ---------------------------------------------------------------------------
__global__ __launch_bounds__(256, 2)
void k_gemm_relu(const u16* __restrict__ A, const u16* __restrict__ B,
                 const float* __restrict__ bias, u16* __restrict__ C,
                 int N, int K)
{
    __shared__ __align__(16) u16 As[128 * 64];
    __shared__ __align__(16) u16 Bs[128 * 64];
    const int t = threadIdx.x, l = t & 63, w = t >> 6;
    const int m0 = blockIdx.y * 128, n0 = blockIdx.x * 128;   // x = column!
    const int lr8 = l >> 3;                 // row within 8-row staging chunk
    const int lc8 = (l & 7) ^ lr8;          // swizzled 16B chunk to fetch
    const u16* Ab = A + (size_t)(m0 + w * 32 + lr8) * K + lc8 * 8;
    const u16* Bb = B + (size_t)(n0 + w * 32 + lr8) * K + lc8 * 8;
    f32x4 acc[4][4] = {};
    const int wr = (w >> 1) * 64, wc = (w & 1) * 64;
    const int lrow = l & 15, lq = l >> 4, s = lrow & 7;

    for (int k0 = 0; k0 < K; k0 += 64) {
        __syncthreads();
#pragma unroll
        for (int q = 0; q < 4; ++q) {
            gll16(&As[(w * 32 + q * 8) * 64], Ab + (size_t)q * 8 * K + k0);
            gll16(&Bs[(w * 32 + q * 8) * 64], Bb + (size_t)q * 8 * K + k0);
        }
        __syncthreads();
#pragma unroll
        for (int kk8 = 0; kk8 < 8; kk8 += 4) {
            const int co = ((kk8 + lq) ^ s) * 8;
            bf16x8 af[4], bfr[4];
#pragma unroll
            for (int mi = 0; mi < 4; ++mi)
                af[mi] = *(const bf16x8*)&As[(wr + mi * 16 + lrow) * 64 + co];
#pragma unroll
            for (int ni = 0; ni < 4; ++ni)
                bfr[ni] = *(const bf16x8*)&Bs[(wc + ni * 16 + lrow) * 64 + co];
#pragma unroll
            for (int mi = 0; mi < 4; ++mi)
#pragma unroll
                for (int ni = 0; ni < 4; ++ni)
                    acc[mi][ni] = MFMA16(af[mi], bfr[ni], acc[mi][ni]);
        }
    }
    const int rq = (l >> 4) * 4;
#pragma unroll
    for (int ni = 0; ni < 4; ++ni) {
        const int col = n0 + wc + ni * 16 + lrow;
        const float bv = bias[col];
#pragma unroll
        for (int mi = 0; mi < 4; ++mi) {
            const int rbase = m0 + wr + mi * 16 + rq;
#pragma unroll
            for (int v = 0; v < 4; ++v) {
                float x = fmaxf(acc[mi][ni][v] + bv, 0.0f);
                C[(size_t)(rbase + v) * N + col] = (u16)(pkbf(x, 0.0f) & 0xFFFF);
            }
        }
    }
}

// ---------------------------------------------------------------------------
// out[i,j] = out[j,i] = sigmoid(h3[r,:512] . Ws + bs). One wave per tri-row.
// ---------------------------------------------------------------------------
__global__ __launch_bounds__(256)
void k_head(const u16* __restrict__ h3, const float* __restrict__ Wsv,
            const float* __restrict__ bsv, float* __restrict__ out, int row0)
{
    const int t = threadIdx.x, l = t & 63, wv = t >> 6;
    const int rl = blockIdx.x * 4 + wv;
    if (row0 + rl >= TRI) return;
    const u16x8 hv = *(const u16x8*)(h3 + (size_t)rl * 512 + l * 8);
    const f32x4 w0 = ((const f32x4*)Wsv)[l * 2];
    const f32x4 w1 = ((const f32x4*)Wsv)[l * 2 + 1];
    float hs[8];
#pragma unroll
    for (int e = 0; e < 8; ++e) {
        union { unsigned int i; float f; } v;
        v.i = ((unsigned int)hv[e]) << 16;
        hs[e] = v.f;
    }
    float s = hs[0] * w0.x + hs[1] * w0.y + hs[2] * w0.z + hs[3] * w0.w
            + hs[4] * w1.x + hs[5] * w1.y + hs[6] * w1.z + hs[7] * w1.w;
#pragma unroll
    for (int off = 32; off >= 1; off >>= 1) s += __shfl_down(s, off, 64);
    if (l == 0) {
        float v = 1.0f / (1.0f + __expf(-(s + bsv[0])));
        int pi, pj; tri_decode(row0 + rl, pi, pj);
        out[pi * NTRK + pj] = v;
        out[pj * NTRK + pi] = v;
    }
}

// ---------------------------------------------------------------------------
extern "C" void kernel_launch(void* const* d_in, const int* in_sizes, int n_in,
                              void* d_out, int out_size, void* d_ws, size_t ws_size,
                              hipStream_t stream)
{
    const float* f   = (const float*)d_in[0];
    const float* Wc1 = (const float*)d_in[1];
    const float* bc1 = (const float*)d_in[2];
    const float* W1  = (const float*)d_in[3];
    const float* b1  = (const float*)d_in[4];
    const float* W2  = (const float*)d_in[5];
    const float* b2  = (const float*)d_in[6];
    const float* W3  = (const float*)d_in[7];
    const float* b3  = (const float*)d_in[8];
    const float* Wsv = (const float*)d_in[9];
    const float* bsv = (const float*)d_in[10];
    float* out = (float*)d_out;

    char* wsb = (char*)d_ws;
    size_t off = 0;
    u16* Wc1b = (u16*)(wsb + off); off += (size_t)4096 * 4096 * 2;
    u16* W1b  = (u16*)(wsb + off); off += (size_t)2048 * 4096 * 2;
    u16* W2b  = (u16*)(wsb + off); off += (size_t)1024 * 2048 * 2;
    u16* W3b  = (u16*)(wsb + off); off += (size_t)512  * 1024 * 2;
    u16* fb   = (u16*)(wsb + off); off += (size_t)192  * 4096 * 2;
    float* g  = (float*)(wsb + off); off += (size_t)192 * 4096 * 4;
    const size_t fixed = off;

    // chunk rows (mult of 128): need dist + h1 + h2 + h3 = R*15360 bytes
    const int Rcand[6] = {18688, 9344, 4736, 2432, 1280, 384};
    int R = 128;
    for (int c = 0; c < 6; ++c) {
        size_t need = fixed + (size_t)Rcand[c] * 15360;
        if (need <= ws_size) { R = Rcand[c]; break; }
    }
    u16* dist = (u16*)(wsb + fixed);
    u16* h1 = dist + (size_t)R * 4096;
    u16* h2 = h1 + (size_t)R * 2048;
    u16* h3 = h2 + (size_t)R * 1024;

    k_cvt<<<512, 256, 0, stream>>>(Wc1, Wc1b, 4096 * 4096 / 4);
    k_cvt<<<512, 256, 0, stream>>>(W1,  W1b,  2048 * 4096 / 4);
    k_cvt<<<256, 256, 0, stream>>>(W2,  W2b,  1024 * 2048 / 4);
    k_cvt<<<128, 256, 0, stream>>>(W3,  W3b,  512  * 1024 / 4);
    k_cvt<<<128, 256, 0, stream>>>(f,   fb,   192  * 4096 / 4);

    k_cam<<<dim3(3, 32), 256, 0, stream>>>(fb, Wc1b, bc1, f, g);

    for (int r0 = 0; r0 < TRI; r0 += R) {
        int rows = TRIP - r0; if (rows > R) rows = R;   // mult of 128
        k_distgen<<<dim3(2, rows), 256, 0, stream>>>(g, dist, r0);
        k_gemm_relu<<<dim3(16, rows / 128), 256, 0, stream>>>(dist, W1b, b1, h1, 2048, 4096);
        k_gemm_relu<<<dim3(8,  rows / 128), 256, 0, stream>>>(h1, W2b, b2, h2, 1024, 2048);
        k_gemm_relu<<<dim3(4,  rows / 128), 256, 0, stream>>>(h2, W3b, b3, h3, 512, 1024);
        k_head<<<dim3(rows / 4), 256, 0, stream>>>(h3, Wsv, bsv, out, r0);
    }
}

// Round 8
// 732.451 us; speedup vs baseline: 1.6226x; 1.0221x over previous
//
#include <hip/hip_runtime.h>
#include <hip/hip_bf16.h>

// ---------------------------------------------------------------------------
// MCT tracklet-affinity pipeline. fp32 in/out, bf16 MFMA internally.
//   g    = f - relu(f @ Wc1^T + bc1)             [192,4096] fp32 in ws
//   dist = |g_i - g_j| for upper-tri rows        [R,4096] bf16, materialized
//   h1   = relu(dist @ W1^T + b1)                [R,2048] bf16
//   h2   = relu(h1 @ W2^T + b2)                  [R,1024]
//   h3   = relu(h2 @ W3^T + b3)                  [R,512]
//   A[i,j]=A[j,i]=sigmoid(h3 . Ws + bs)          [192,192] fp32
// Round-8 (round-7 GEMM core kept: 16x16x32 MFMA + XOR-swizzled LDS = zero
// bank conflicts, 924 TF = m97 plateau):
//  - ws aliasing: Wc1b dead after k_cam -> overlaid by chunk region; h2/h3
//    overlay dist (dead after L1). Single-chunk R=18688 if ws permits.
//  - k_cam split-K=4 (96 -> 384 blocks; partials in ws, k_gfin combines).
//  - one fused k_cvt_all instead of 5 serialized cvt launches.
// ---------------------------------------------------------------------------

typedef unsigned short u16;
typedef __attribute__((ext_vector_type(8))) short    bf16x8;
typedef __attribute__((ext_vector_type(8))) unsigned short u16x8;
typedef __attribute__((ext_vector_type(4))) float    f32x4;

#define MFMA16(a, b, c) __builtin_amdgcn_mfma_f32_16x16x32_bf16((a), (b), (c), 0, 0, 0)

#define NTRK 192
#define TRI  18528         /* 192*193/2 upper-tri rows incl diagonal */
#define TRIP 18688         /* padded to 146*128 */

__device__ __forceinline__ unsigned int pkbf(float lo, float hi) {
    __hip_bfloat162 h2 = __float22bfloat162_rn(make_float2(lo, hi));
    return *reinterpret_cast<unsigned int*>(&h2);
}
__device__ __forceinline__ void gll16(void* lds_uniform, const void* gsrc) {
    __builtin_amdgcn_global_load_lds(
        (__attribute__((address_space(1))) void*)(gsrc),
        (__attribute__((address_space(3))) void*)(lds_uniform),
        16, 0, 0);
}
// triangle row r -> (i,j), i<=j. T(i) = i*(385-i)/2. Clamped for padding rows.
__device__ __forceinline__ void tri_decode(int r, int& oi, int& oj) {
    double a = 192.5;
    int i = (int)(a - sqrt(a * a - 2.0 * (double)r));
    i = i < 0 ? 0 : (i > 191 ? 191 : i);
    while (i < 191 && (i + 1) * (385 - (i + 1)) / 2 <= r) ++i;
    while (i > 0 && i * (385 - i) / 2 > r) --i;
    int j = i + (r - i * (385 - i) / 2);
    oi = i; oj = j > 191 ? 191 : j;
}

// ---------------------------------------------------------------------------
// All five fp32->bf16 conversions in ONE launch. Segment sizes in f32x4:
// Wc1 4194304 | W1 2097152 | W2 524288 | W3 131072 | f 196608  (sum 7143424)
// ---------------------------------------------------------------------------
#define CVT_N 7143424
__global__ __launch_bounds__(256)
void k_cvt_all(const float* __restrict__ s0, u16* __restrict__ d0,
               const float* __restrict__ s1, u16* __restrict__ d1,
               const float* __restrict__ s2, u16* __restrict__ d2,
               const float* __restrict__ s3, u16* __restrict__ d3,
               const float* __restrict__ s4, u16* __restrict__ d4)
{
    int i = blockIdx.x * 256 + threadIdx.x;
    if (i >= CVT_N) return;
    const float* s; u16* d; int j;
    if      (i < 4194304) { s = s0; d = d0; j = i; }
    else if (i < 6291456) { s = s1; d = d1; j = i - 4194304; }
    else if (i < 6815744) { s = s2; d = d2; j = i - 6291456; }
    else if (i < 6946816) { s = s3; d = d3; j = i - 6815744; }
    else                  { s = s4; d = d4; j = i - 6946816; }
    f32x4 v = ((const f32x4*)s)[j];
    ((uint2*)d)[j] = make_uint2(pkbf(v.x, v.y), pkbf(v.z, v.w));
}

// ---------------------------------------------------------------------------
// cam partials: camp[z][row][col] = (fb @ Wc1b^T) over k in [z*1024,(z+1)*1024)
// M=192,N=4096. BM=64,BN=128,BK=64, split-K=4 via blockIdx.z. grid (3,32,4).
// XOR-swizzled staging/reads (round-7).
// ---------------------------------------------------------------------------
__global__ __launch_bounds__(256, 2)
void k_cam(const u16* __restrict__ fb, const u16* __restrict__ Wc1b,
           float* __restrict__ camp)
{
    __shared__ __align__(16) u16 As[64 * 64];
    __shared__ __align__(16) u16 Bs[128 * 64];
    const int t = threadIdx.x, l = t & 63, w = t >> 6;
    const int m0 = blockIdx.x * 64, n0 = blockIdx.y * 128;
    const int kbeg = blockIdx.z * 1024, kend = kbeg + 1024;
    const int lr8 = l >> 3;
    const int lc8 = (l & 7) ^ lr8;
    const u16* Ab = fb   + (size_t)(m0 + w * 16 + lr8) * 4096 + lc8 * 8;
    const u16* Bb = Wc1b + (size_t)(n0 + w * 32 + lr8) * 4096 + lc8 * 8;
    f32x4 acc[2][4] = {};
    const int wr = (w >> 1) * 32, wc = (w & 1) * 64;
    const int lrow = l & 15, lq = l >> 4, s = lrow & 7;

    for (int k0 = kbeg; k0 < kend; k0 += 64) {
        __syncthreads();
#pragma unroll
        for (int q = 0; q < 2; ++q)
            gll16(&As[(w * 16 + q * 8) * 64], Ab + (size_t)q * 8 * 4096 + k0);
#pragma unroll
        for (int q = 0; q < 4; ++q)
            gll16(&Bs[(w * 32 + q * 8) * 64], Bb + (size_t)q * 8 * 4096 + k0);
        __syncthreads();
#pragma unroll
        for (int kk8 = 0; kk8 < 8; kk8 += 4) {
            const int co = ((kk8 + lq) ^ s) * 8;
            bf16x8 af[2], bfr[4];
#pragma unroll
            for (int mi = 0; mi < 2; ++mi)
                af[mi] = *(const bf16x8*)&As[(wr + mi * 16 + lrow) * 64 + co];
#pragma unroll
            for (int ni = 0; ni < 4; ++ni)
                bfr[ni] = *(const bf16x8*)&Bs[(wc + ni * 16 + lrow) * 64 + co];
#pragma unroll
            for (int mi = 0; mi < 2; ++mi)
#pragma unroll
                for (int ni = 0; ni < 4; ++ni)
                    acc[mi][ni] = MFMA16(af[mi], bfr[ni], acc[mi][ni]);
        }
    }
    float* cz = camp + (size_t)blockIdx.z * 192 * 4096;
    const int rq = (l >> 4) * 4;
#pragma unroll
    for (int ni = 0; ni < 4; ++ni) {
        const int col = n0 + wc + ni * 16 + lrow;
#pragma unroll
        for (int mi = 0; mi < 2; ++mi) {
            const int rbase = m0 + wr + mi * 16 + rq;
#pragma unroll
            for (int v = 0; v < 4; ++v)
                cz[(size_t)(rbase + v) * 4096 + col] = acc[mi][ni][v];
        }
    }
}

// ---------------------------------------------------------------------------
// g = f - relu(sum_z camp[z] + bc1). 196608 f32x4 groups, grid 768.
// ---------------------------------------------------------------------------
__global__ __launch_bounds__(256)
void k_gfin(const float* __restrict__ camp, const float* __restrict__ bc1,
            const float* __restrict__ f, float* __restrict__ g)
{
    const int i = blockIdx.x * 256 + threadIdx.x;       // < 196608
    const int col4 = (i * 4) & 4095;
    f32x4 p0 = ((const f32x4*)camp)[i];
    f32x4 p1 = ((const f32x4*)(camp + 786432))[i];
    f32x4 p2 = ((const f32x4*)(camp + 1572864))[i];
    f32x4 p3 = ((const f32x4*)(camp + 2359296))[i];
    f32x4 b = *(const f32x4*)(bc1 + col4);
    f32x4 fv = ((const f32x4*)f)[i];
    f32x4 r;
    r.x = fv.x - fmaxf(p0.x + p1.x + p2.x + p3.x + b.x, 0.0f);
    r.y = fv.y - fmaxf(p0.y + p1.y + p2.y + p3.y + b.y, 0.0f);
    r.z = fv.z - fmaxf(p0.z + p1.z + p2.z + p3.z + b.z, 0.0f);
    r.w = fv.w - fmaxf(p0.w + p1.w + p2.w + p3.w + b.w, 0.0f);
    ((f32x4*)g)[i] = r;
}

// ---------------------------------------------------------------------------
// dist[r, :] = bf16(|g_i - g_j|). One 16B chunk per thread. grid (2, rows).
// ---------------------------------------------------------------------------
__global__ __launch_bounds__(256)
void k_distgen(const float* __restrict__ g, u16* __restrict__ dist, int row0)
{
    const int r = blockIdx.y;
    const int c = blockIdx.x * 256 + threadIdx.x;       // chunk 0..511
    int pi, pj; tri_decode(row0 + r, pi, pj);
    const float* gi = g + (size_t)pi * 4096 + c * 8;
    const float* gj = g + (size_t)pj * 4096 + c * 8;
    f32x4 a0 = ((const f32x4*)gi)[0], a1 = ((const f32x4*)gi)[1];
    f32x4 b0 = ((const f32x4*)gj)[0], b1 = ((const f32x4*)gj)[1];
    uint4 o;
    o.x = pkbf(fabsf(b0.x - a0.x), fabsf(b0.y - a0.y));
    o.y = pkbf(fabsf(b0.z - a0.z), fabsf(b0.w - a0.w));
    o.z = pkbf(fabsf(b1.x - a1.x), fabsf(b1.y - a1.y));
    o.w = pkbf(fabsf(b1.z - a1.z), fabsf(b1.w - a1.w));
    *reinterpret_cast<uint4*>(dist + (size_t)r * 4096 + c * 8) = o;
}

// ---------------------------------------------------------------------------
// C = relu(A @ B^T + bias), bf16, 16x16x32 MFMA. BM=BN=128, BK=64, 256 thr,
// wave tile 64x64. grid (N/128, M/128): x = COLUMN tile (fast).
// XOR-swizzled LDS: stage chunk (l&7)^(l>>3), read chunk (ck)^(row&7).
// ---------------------------------------------------------------------------
__global__ __launch_bounds__(256, 2)
void k_gemm_relu(const u16* __restrict__ A, const u16* __restrict__ B,
                 const float* __restrict__ bias, u16* __restrict__ C,
                 int N, int K)
{
    __shared__ __align__(16) u16 As[128 * 64];
    __shared__ __align__(16) u16 Bs[128 * 64];
    const int t = threadIdx.x, l = t & 63, w = t >> 6;
    const int m0 = blockIdx.y * 128, n0 = blockIdx.x * 128;   // x = column!
    const int lr8 = l >> 3;
    const int lc8 = (l & 7) ^ lr8;
    const u16* Ab = A + (size_t)(m0 + w * 32 + lr8) * K + lc8 * 8;
    const u16* Bb = B + (size_t)(n0 + w * 32 + lr8) * K + lc8 * 8;
    f32x4 acc[4][4] = {};
    const int wr = (w >> 1) * 64, wc = (w & 1) * 64;
    const int lrow = l & 15, lq = l >> 4, s = lrow & 7;

    for (int k0 = 0; k0 < K; k0 += 64) {
        __syncthreads();
#pragma unroll
        for (int q = 0; q < 4; ++q) {
            gll16(&As[(w * 32 + q * 8) * 64], Ab + (size_t)q * 8 * K + k0);
            gll16(&Bs[(w * 32 + q * 8) * 64], Bb + (size_t)q * 8 * K + k0);
        }
        __syncthreads();
#pragma unroll
        for (int kk8 = 0; kk8 < 8; kk8 += 4) {
            const int co = ((kk8 + lq) ^ s) * 8;
            bf16x8 af[4], bfr[4];
#pragma unroll
            for (int mi = 0; mi < 4; ++mi)
                af[mi] = *(const bf16x8*)&As[(wr + mi * 16 + lrow) * 64 + co];
#pragma unroll
            for (int ni = 0; ni < 4; ++ni)
                bfr[ni] = *(const bf16x8*)&Bs[(wc + ni * 16 + lrow) * 64 + co];
#pragma unroll
            for (int mi = 0; mi < 4; ++mi)
#pragma unroll
                for (int ni = 0; ni < 4; ++ni)
                    acc[mi][ni] = MFMA16(af[mi], bfr[ni], acc[mi][ni]);
        }
    }
    const int rq = (l >> 4) * 4;
#pragma unroll
    for (int ni = 0; ni < 4; ++ni) {
        const int col = n0 + wc + ni * 16 + lrow;
        const float bv = bias[col];
#pragma unroll
        for (int mi = 0; mi < 4; ++mi) {
            const int rbase = m0 + wr + mi * 16 + rq;
#pragma unroll
            for (int v = 0; v < 4; ++v) {
                float x = fmaxf(acc[mi][ni][v] + bv, 0.0f);
                C[(size_t)(rbase + v) * N + col] = (u16)(pkbf(x, 0.0f) & 0xFFFF);
            }
        }
    }
}

// ---------------------------------------------------------------------------
// out[i,j] = out[j,i] = sigmoid(h3[r,:512] . Ws + bs). One wave per tri-row.
// ---------------------------------------------------------------------------
__global__ __launch_bounds__(256)
void k_head(const u16* __restrict__ h3, const float* __restrict__ Wsv,
            const float* __restrict__ bsv, float* __restrict__ out, int row0)
{
    const int t = threadIdx.x, l = t & 63, wv = t >> 6;
    const int rl = blockIdx.x * 4 + wv;
    if (row0 + rl >= TRI) return;
    const u16x8 hv = *(const u16x8*)(h3 + (size_t)rl * 512 + l * 8);
    const f32x4 w0 = ((const f32x4*)Wsv)[l * 2];
    const f32x4 w1 = ((const f32x4*)Wsv)[l * 2 + 1];
    float hs[8];
#pragma unroll
    for (int e = 0; e < 8; ++e) {
        union { unsigned int i; float f; } v;
        v.i = ((unsigned int)hv[e]) << 16;
        hs[e] = v.f;
    }
    float s = hs[0] * w0.x + hs[1] * w0.y + hs[2] * w0.z + hs[3] * w0.w
            + hs[4] * w1.x + hs[5] * w1.y + hs[6] * w1.z + hs[7] * w1.w;
#pragma unroll
    for (int off = 32; off >= 1; off >>= 1) s += __shfl_down(s, off, 64);
    if (l == 0) {
        float v = 1.0f / (1.0f + __expf(-(s + bsv[0])));
        int pi, pj; tri_decode(row0 + rl, pi, pj);
        out[pi * NTRK + pj] = v;
        out[pj * NTRK + pi] = v;
    }
}

// ---------------------------------------------------------------------------
extern "C" void kernel_launch(void* const* d_in, const int* in_sizes, int n_in,
                              void* d_out, int out_size, void* d_ws, size_t ws_size,
                              hipStream_t stream)
{
    const float* f   = (const float*)d_in[0];
    const float* Wc1 = (const float*)d_in[1];
    const float* bc1 = (const float*)d_in[2];
    const float* W1  = (const float*)d_in[3];
    const float* b1  = (const float*)d_in[4];
    const float* W2  = (const float*)d_in[5];
    const float* b2  = (const float*)d_in[6];
    const float* W3  = (const float*)d_in[7];
    const float* b3  = (const float*)d_in[8];
    const float* Wsv = (const float*)d_in[9];
    const float* bsv = (const float*)d_in[10];
    float* out = (float*)d_out;

    // ---- workspace layout ----
    // persistent: W1b 16M | W2b 4M | W3b 1M | fb 1.5M | g 3M | camp 12M
    // chunk region (from chunkbase): Wc1b (32M, dead after k_cam) overlaid by
    //   dist (8192R) + h1 (4096R); h2 (2048R) + h3 (1024R) overlay dist.
    char* wsb = (char*)d_ws;
    size_t off = 0;
    u16*   W1b  = (u16*)(wsb + off);  off += (size_t)2048 * 4096 * 2;
    u16*   W2b  = (u16*)(wsb + off);  off += (size_t)1024 * 2048 * 2;
    u16*   W3b  = (u16*)(wsb + off);  off += (size_t)512  * 1024 * 2;
    u16*   fb   = (u16*)(wsb + off);  off += (size_t)192  * 4096 * 2;
    float* g    = (float*)(wsb + off); off += (size_t)192 * 4096 * 4;
    float* camp = (float*)(wsb + off); off += (size_t)4 * 192 * 4096 * 4;
    const size_t chunkbase = off;
    u16* Wc1b = (u16*)(wsb + chunkbase);
    const size_t wc1b_bytes = (size_t)4096 * 4096 * 2;

    const int Rcand[6] = {18688, 9344, 4736, 2432, 1280, 640};
    int R = 128;
    for (int c = 0; c < 6; ++c) {
        size_t chunk = (size_t)Rcand[c] * 12288;
        if (chunk < wc1b_bytes) chunk = wc1b_bytes;
        if (chunkbase + chunk <= ws_size) { R = Rcand[c]; break; }
    }
    u16* dist = (u16*)(wsb + chunkbase);
    u16* h1 = dist + (size_t)R * 4096;
    u16* h2 = dist;                       // overlays dist (dead after L1)
    u16* h3 = h2 + (size_t)R * 1024;

    k_cvt_all<<<(CVT_N + 255) / 256, 256, 0, stream>>>(
        Wc1, Wc1b, W1, W1b, W2, W2b, W3, W3b, f, fb);
    k_cam<<<dim3(3, 32, 4), 256, 0, stream>>>(fb, Wc1b, camp);
    k_gfin<<<768, 256, 0, stream>>>(camp, bc1, f, g);

    for (int r0 = 0; r0 < TRI; r0 += R) {
        int rows = TRIP - r0; if (rows > R) rows = R;   // mult of 128
        k_distgen<<<dim3(2, rows), 256, 0, stream>>>(g, dist, r0);
        k_gemm_relu<<<dim3(16, rows / 128), 256, 0, stream>>>(dist, W1b, b1, h1, 2048, 4096);
        k_gemm_relu<<<dim3(8,  rows / 128), 256, 0, stream>>>(h1, W2b, b2, h2, 1024, 2048);
        k_gemm_relu<<<dim3(4,  rows / 128), 256, 0, stream>>>(h2, W3b, b3, h3, 512, 1024);
        k_head<<<dim3(rows / 4), 256, 0, stream>>>(h3, Wsv, bsv, out, r0);
    }
}

// Round 9
// 657.692 us; speedup vs baseline: 1.8070x; 1.1137x over previous
//
#include <hip/hip_runtime.h>
#include <hip/hip_bf16.h>

// ---------------------------------------------------------------------------
// MCT tracklet-affinity pipeline. fp32 in/out, bf16 MFMA internally.
//   g    = f - relu(f @ Wc1^T + bc1)             [192,4096] fp32 in ws
//   dist = |g_i - g_j| for upper-tri rows        [R,4096] bf16, materialized
//   h1   = relu(dist @ W1^T + b1)                [R,2048] bf16
//   h2   = relu(h1 @ W2^T + b2)                  [R,1024]  (overlays dist)
//   logit[r] += relu(h2 @ W3^T + b3) . Ws        (k_gemm3: fused L3+head dot,
//                                                 fp32 atomicAdd per row)
//   A[i,j]=A[j,i]=sigmoid(logit + bs)            (k_sig, once at end)
// Round-9: L3+head fused (h3 never materialized); chunkbase tightened to
// 25.6 MB (Wc1b + camp overlay the chunk region — dead before chunk loop);
// asymmetric chunk ladder maximizes first chunk (R=14336 fits the measured
// ws floor of 203.8 MB). GEMM core unchanged from round 7: 16x16x32 MFMA,
// XOR-swizzled LDS (0 bank conflicts), x = column tile for XCD L2 locality.
// ---------------------------------------------------------------------------

typedef unsigned short u16;
typedef __attribute__((ext_vector_type(8))) short    bf16x8;
typedef __attribute__((ext_vector_type(8))) unsigned short u16x8;
typedef __attribute__((ext_vector_type(4))) float    f32x4;

#define MFMA16(a, b, c) __builtin_amdgcn_mfma_f32_16x16x32_bf16((a), (b), (c), 0, 0, 0)

#define NTRK 192
#define TRI  18528         /* 192*193/2 upper-tri rows incl diagonal */
#define TRIP 18688         /* padded to 146*128 */

__device__ __forceinline__ unsigned int pkbf(float lo, float hi) {
    __hip_bfloat162 h2 = __float22bfloat162_rn(make_float2(lo, hi));
    return *reinterpret_cast<unsigned int*>(&h2);
}
__device__ __forceinline__ void gll16(void* lds_uniform, const void* gsrc) {
    __builtin_amdgcn_global_load_lds(
        (__attribute__((address_space(1))) void*)(gsrc),
        (__attribute__((address_space(3))) void*)(lds_uniform),
        16, 0, 0);
}
// triangle row r -> (i,j), i<=j. T(i) = i*(385-i)/2. Clamped for padding rows.
__device__ __forceinline__ void tri_decode(int r, int& oi, int& oj) {
    double a = 192.5;
    int i = (int)(a - sqrt(a * a - 2.0 * (double)r));
    i = i < 0 ? 0 : (i > 191 ? 191 : i);
    while (i < 191 && (i + 1) * (385 - (i + 1)) / 2 <= r) ++i;
    while (i > 0 && i * (385 - i) / 2 > r) --i;
    int j = i + (r - i * (385 - i) / 2);
    oi = i; oj = j > 191 ? 191 : j;
}

// ---------------------------------------------------------------------------
// All five fp32->bf16 conversions in ONE launch. Segment sizes in f32x4:
// Wc1 4194304 | W1 2097152 | W2 524288 | W3 131072 | f 196608  (sum 7143424)
// ---------------------------------------------------------------------------
#define CVT_N 7143424
__global__ __launch_bounds__(256)
void k_cvt_all(const float* __restrict__ s0, u16* __restrict__ d0,
               const float* __restrict__ s1, u16* __restrict__ d1,
               const float* __restrict__ s2, u16* __restrict__ d2,
               const float* __restrict__ s3, u16* __restrict__ d3,
               const float* __restrict__ s4, u16* __restrict__ d4)
{
    int i = blockIdx.x * 256 + threadIdx.x;
    if (i >= CVT_N) return;
    const float* s; u16* d; int j;
    if      (i < 4194304) { s = s0; d = d0; j = i; }
    else if (i < 6291456) { s = s1; d = d1; j = i - 4194304; }
    else if (i < 6815744) { s = s2; d = d2; j = i - 6291456; }
    else if (i < 6946816) { s = s3; d = d3; j = i - 6815744; }
    else                  { s = s4; d = d4; j = i - 6946816; }
    f32x4 v = ((const f32x4*)s)[j];
    ((uint2*)d)[j] = make_uint2(pkbf(v.x, v.y), pkbf(v.z, v.w));
}

// ---------------------------------------------------------------------------
// cam partials: camp[z][row][col] = (fb @ Wc1b^T) over k in [z*1024,(z+1)*1024)
// M=192,N=4096. BM=64,BN=128,BK=64, split-K=4 via blockIdx.z. grid (3,32,4).
// ---------------------------------------------------------------------------
__global__ __launch_bounds__(256, 2)
void k_cam(const u16* __restrict__ fb, const u16* __restrict__ Wc1b,
           float* __restrict__ camp)
{
    __shared__ __align__(16) u16 As[64 * 64];
    __shared__ __align__(16) u16 Bs[128 * 64];
    const int t = threadIdx.x, l = t & 63, w = t >> 6;
    const int m0 = blockIdx.x * 64, n0 = blockIdx.y * 128;
    const int kbeg = blockIdx.z * 1024, kend = kbeg + 1024;
    const int lr8 = l >> 3;
    const int lc8 = (l & 7) ^ lr8;
    const u16* Ab = fb   + (size_t)(m0 + w * 16 + lr8) * 4096 + lc8 * 8;
    const u16* Bb = Wc1b + (size_t)(n0 + w * 32 + lr8) * 4096 + lc8 * 8;
    f32x4 acc[2][4] = {};
    const int wr = (w >> 1) * 32, wc = (w & 1) * 64;
    const int lrow = l & 15, lq = l >> 4, s = lrow & 7;

    for (int k0 = kbeg; k0 < kend; k0 += 64) {
        __syncthreads();
#pragma unroll
        for (int q = 0; q < 2; ++q)
            gll16(&As[(w * 16 + q * 8) * 64], Ab + (size_t)q * 8 * 4096 + k0);
#pragma unroll
        for (int q = 0; q < 4; ++q)
            gll16(&Bs[(w * 32 + q * 8) * 64], Bb + (size_t)q * 8 * 4096 + k0);
        __syncthreads();
#pragma unroll
        for (int kk8 = 0; kk8 < 8; kk8 += 4) {
            const int co = ((kk8 + lq) ^ s) * 8;
            bf16x8 af[2], bfr[4];
#pragma unroll
            for (int mi = 0; mi < 2; ++mi)
                af[mi] = *(const bf16x8*)&As[(wr + mi * 16 + lrow) * 64 + co];
#pragma unroll
            for (int ni = 0; ni < 4; ++ni)
                bfr[ni] = *(const bf16x8*)&Bs[(wc + ni * 16 + lrow) * 64 + co];
#pragma unroll
            for (int mi = 0; mi < 2; ++mi)
#pragma unroll
                for (int ni = 0; ni < 4; ++ni)
                    acc[mi][ni] = MFMA16(af[mi], bfr[ni], acc[mi][ni]);
        }
    }
    float* cz = camp + (size_t)blockIdx.z * 192 * 4096;
    const int rq = (l >> 4) * 4;
#pragma unroll
    for (int ni = 0; ni < 4; ++ni) {
        const int col = n0 + wc + ni * 16 + lrow;
#pragma unroll
        for (int mi = 0; mi < 2; ++mi) {
            const int rbase = m0 + wr + mi * 16 + rq;
#pragma unroll
            for (int v = 0; v < 4; ++v)
                cz[(size_t)(rbase + v) * 4096 + col] = acc[mi][ni][v];
        }
    }
}

// ---------------------------------------------------------------------------
// g = f - relu(sum_z camp[z] + bc1). 196608 f32x4 groups, grid 768.
// ---------------------------------------------------------------------------
__global__ __launch_bounds__(256)
void k_gfin(const float* __restrict__ camp, const float* __restrict__ bc1,
            const float* __restrict__ f, float* __restrict__ g)
{
    const int i = blockIdx.x * 256 + threadIdx.x;       // < 196608
    const int col4 = (i * 4) & 4095;
    f32x4 p0 = ((const f32x4*)camp)[i];
    f32x4 p1 = ((const f32x4*)(camp + 786432))[i];
    f32x4 p2 = ((const f32x4*)(camp + 1572864))[i];
    f32x4 p3 = ((const f32x4*)(camp + 2359296))[i];
    f32x4 b = *(const f32x4*)(bc1 + col4);
    f32x4 fv = ((const f32x4*)f)[i];
    f32x4 r;
    r.x = fv.x - fmaxf(p0.x + p1.x + p2.x + p3.x + b.x, 0.0f);
    r.y = fv.y - fmaxf(p0.y + p1.y + p2.y + p3.y + b.y, 0.0f);
    r.z = fv.z - fmaxf(p0.z + p1.z + p2.z + p3.z + b.z, 0.0f);
    r.w = fv.w - fmaxf(p0.w + p1.w + p2.w + p3.w + b.w, 0.0f);
    ((f32x4*)g)[i] = r;
}

// ---------------------------------------------------------------------------
// dist[r, :] = bf16(|g_i - g_j|). One 16B chunk per thread. grid (2, rows).
// ---------------------------------------------------------------------------
__global__ __launch_bounds__(256)
void k_distgen(const float* __restrict__ g, u16* __restrict__ dist, int row0)
{
    const int r = blockIdx.y;
    const int c = blockIdx.x * 256 + threadIdx.x;       // chunk 0..511
    int pi, pj; tri_decode(row0 + r, pi, pj);
    const float* gi = g + (size_t)pi * 4096 + c * 8;
    const float* gj = g + (size_t)pj * 4096 + c * 8;
    f32x4 a0 = ((const f32x4*)gi)[0], a1 = ((const f32x4*)gi)[1];
    f32x4 b0 = ((const f32x4*)gj)[0], b1 = ((const f32x4*)gj)[1];
    uint4 o;
    o.x = pkbf(fabsf(b0.x - a0.x), fabsf(b0.y - a0.y));
    o.y = pkbf(fabsf(b0.z - a0.z), fabsf(b0.w - a0.w));
    o.z = pkbf(fabsf(b1.x - a1.x), fabsf(b1.y - a1.y));
    o.w = pkbf(fabsf(b1.z - a1.z), fabsf(b1.w - a1.w));
    *reinterpret_cast<uint4*>(dist + (size_t)r * 4096 + c * 8) = o;
}

// ---------------------------------------------------------------------------
// C = relu(A @ B^T + bias), bf16, 16x16x32 MFMA. BM=BN=128, BK=64, 256 thr,
// wave tile 64x64. grid (N/128, M/128): x = COLUMN tile (fast).
// XOR-swizzled LDS: stage chunk (l&7)^(l>>3), read chunk (ck)^(row&7).
// ---------------------------------------------------------------------------
__global__ __launch_bounds__(256, 2)
void k_gemm_relu(const u16* __restrict__ A, const u16* __restrict__ B,
                 const float* __restrict__ bias, u16* __restrict__ C,
                 int N, int K)
{
    __shared__ __align__(16) u16 As[128 * 64];
    __shared__ __align__(16) u16 Bs[128 * 64];
    const int t = threadIdx.x, l = t & 63, w = t >> 6;
    const int m0 = blockIdx.y * 128, n0 = blockIdx.x * 128;   // x = column!
    const int lr8 = l >> 3;
    const int lc8 = (l & 7) ^ lr8;
    const u16* Ab = A + (size_t)(m0 + w * 32 + lr8) * K + lc8 * 8;
    const u16* Bb = B + (size_t)(n0 + w * 32 + lr8) * K + lc8 * 8;
    f32x4 acc[4][4] = {};
    const int wr = (w >> 1) * 64, wc = (w & 1) * 64;
    const int lrow = l & 15, lq = l >> 4, s = lrow & 7;

    for (int k0 = 0; k0 < K; k0 += 64) {
        __syncthreads();
#pragma unroll
        for (int q = 0; q < 4; ++q) {
            gll16(&As[(w * 32 + q * 8) * 64], Ab + (size_t)q * 8 * K + k0);
            gll16(&Bs[(w * 32 + q * 8) * 64], Bb + (size_t)q * 8 * K + k0);
        }
        __syncthreads();
#pragma unroll
        for (int kk8 = 0; kk8 < 8; kk8 += 4) {
            const int co = ((kk8 + lq) ^ s) * 8;
            bf16x8 af[4], bfr[4];
#pragma unroll
            for (int mi = 0; mi < 4; ++mi)
                af[mi] = *(const bf16x8*)&As[(wr + mi * 16 + lrow) * 64 + co];
#pragma unroll
            for (int ni = 0; ni < 4; ++ni)
                bfr[ni] = *(const bf16x8*)&Bs[(wc + ni * 16 + lrow) * 64 + co];
#pragma unroll
            for (int mi = 0; mi < 4; ++mi)
#pragma unroll
                for (int ni = 0; ni < 4; ++ni)
                    acc[mi][ni] = MFMA16(af[mi], bfr[ni], acc[mi][ni]);
        }
    }
    const int rq = (l >> 4) * 4;
#pragma unroll
    for (int ni = 0; ni < 4; ++ni) {
        const int col = n0 + wc + ni * 16 + lrow;
        const float bv = bias[col];
#pragma unroll
        for (int mi = 0; mi < 4; ++mi) {
            const int rbase = m0 + wr + mi * 16 + rq;
#pragma unroll
            for (int v = 0; v < 4; ++v) {
                float x = fmaxf(acc[mi][ni][v] + bv, 0.0f);
                C[(size_t)(rbase + v) * N + col] = (u16)(pkbf(x, 0.0f) & 0xFFFF);
            }
        }
    }
}

// ---------------------------------------------------------------------------
// Fused L3+head: logit[r0+row] += sum_col relu(h2@W3^T + b3)[row,col]*Ws[col].
// Same GEMM core (N=512, K=1024, grid (4, rows/128)). Epilogue: per (mi,v)
// row-slot, dot partial over this lane's 4 cols, butterfly-reduce across the
// 16 lrow lanes (xor masks 1,2,4,8 stay within the l>>4 quad since row is
// determined by l>>4), one fp32 atomicAdd per row-slot from lane lrow==0.
// ---------------------------------------------------------------------------
__global__ __launch_bounds__(256, 2)
void k_gemm3(const u16* __restrict__ A, const u16* __restrict__ B,
             const float* __restrict__ bias, const float* __restrict__ Wsv,
             float* __restrict__ logit, int r0)
{
    const int N = 512, K = 1024;
    __shared__ __align__(16) u16 As[128 * 64];
    __shared__ __align__(16) u16 Bs[128 * 64];
    const int t = threadIdx.x, l = t & 63, w = t >> 6;
    const int m0 = blockIdx.y * 128, n0 = blockIdx.x * 128;
    const int lr8 = l >> 3;
    const int lc8 = (l & 7) ^ lr8;
    const u16* Ab = A + (size_t)(m0 + w * 32 + lr8) * K + lc8 * 8;
    const u16* Bb = B + (size_t)(n0 + w * 32 + lr8) * K + lc8 * 8;
    f32x4 acc[4][4] = {};
    const int wr = (w >> 1) * 64, wc = (w & 1) * 64;
    const int lrow = l & 15, lq = l >> 4, s = lrow & 7;

    for (int k0 = 0; k0 < K; k0 += 64) {
        __syncthreads();
#pragma unroll
        for (int q = 0; q < 4; ++q) {
            gll16(&As[(w * 32 + q * 8) * 64], Ab + (size_t)q * 8 * K + k0);
            gll16(&Bs[(w * 32 + q * 8) * 64], Bb + (size_t)q * 8 * K + k0);
        }
        __syncthreads();
#pragma unroll
        for (int kk8 = 0; kk8 < 8; kk8 += 4) {
            const int co = ((kk8 + lq) ^ s) * 8;
            bf16x8 af[4], bfr[4];
#pragma unroll
            for (int mi = 0; mi < 4; ++mi)
                af[mi] = *(const bf16x8*)&As[(wr + mi * 16 + lrow) * 64 + co];
#pragma unroll
            for (int ni = 0; ni < 4; ++ni)
                bfr[ni] = *(const bf16x8*)&Bs[(wc + ni * 16 + lrow) * 64 + co];
#pragma unroll
            for (int mi = 0; mi < 4; ++mi)
#pragma unroll
                for (int ni = 0; ni < 4; ++ni)
                    acc[mi][ni] = MFMA16(af[mi], bfr[ni], acc[mi][ni]);
        }
    }
    const int rq = (l >> 4) * 4;
    float wv[4], bv[4];
#pragma unroll
    for (int ni = 0; ni < 4; ++ni) {
        const int col = n0 + wc + ni * 16 + lrow;
        wv[ni] = Wsv[col];
        bv[ni] = bias[col];
    }
#pragma unroll
    for (int mi = 0; mi < 4; ++mi) {
#pragma unroll
        for (int v = 0; v < 4; ++v) {
            float p = 0.0f;
#pragma unroll
            for (int ni = 0; ni < 4; ++ni)
                p += fmaxf(acc[mi][ni][v] + bv[ni], 0.0f) * wv[ni];
            p += __shfl_xor(p, 1, 64);
            p += __shfl_xor(p, 2, 64);
            p += __shfl_xor(p, 4, 64);
            p += __shfl_xor(p, 8, 64);
            if (lrow == 0)
                atomicAdd(&logit[r0 + m0 + wr + mi * 16 + rq + v], p);
        }
    }
}

// ---------------------------------------------------------------------------
// out[i,j] = out[j,i] = sigmoid(logit[r] + bs). One thread per tri-row.
// ---------------------------------------------------------------------------
__global__ __launch_bounds__(256)
void k_sig(const float* __restrict__ logit, const float* __restrict__ bsv,
           float* __restrict__ out)
{
    const int r = blockIdx.x * 256 + threadIdx.x;
    if (r >= TRI) return;
    int pi, pj; tri_decode(r, pi, pj);
    float v = 1.0f / (1.0f + __expf(-(logit[r] + bsv[0])));
    out[pi * NTRK + pj] = v;
    out[pj * NTRK + pi] = v;
}

// ---------------------------------------------------------------------------
extern "C" void kernel_launch(void* const* d_in, const int* in_sizes, int n_in,
                              void* d_out, int out_size, void* d_ws, size_t ws_size,
                              hipStream_t stream)
{
    const float* f   = (const float*)d_in[0];
    const float* Wc1 = (const float*)d_in[1];
    const float* bc1 = (const float*)d_in[2];
    const float* W1  = (const float*)d_in[3];
    const float* b1  = (const float*)d_in[4];
    const float* W2  = (const float*)d_in[5];
    const float* b2  = (const float*)d_in[6];
    const float* W3  = (const float*)d_in[7];
    const float* b3  = (const float*)d_in[8];
    const float* Wsv = (const float*)d_in[9];
    const float* bsv = (const float*)d_in[10];
    float* out = (float*)d_out;

    // ---- workspace layout ----
    // persistent: W1b 16M | W2b 4M | W3b 1M | fb 1.5M | g 3M | logit 75K
    // overlay region at chunkbase:
    //   phase A: Wc1b (32M) + camp (12M)   [dead before chunk loop]
    //   phase B: dist (8192R) + h1 (4096R); h2 (2048R) overlays dist.
    char* wsb = (char*)d_ws;
    size_t off = 0;
    u16*   W1b   = (u16*)(wsb + off);  off += (size_t)2048 * 4096 * 2;
    u16*   W2b   = (u16*)(wsb + off);  off += (size_t)1024 * 2048 * 2;
    u16*   W3b   = (u16*)(wsb + off);  off += (size_t)512  * 1024 * 2;
    u16*   fb    = (u16*)(wsb + off);  off += (size_t)192  * 4096 * 2;
    float* g     = (float*)(wsb + off); off += (size_t)192 * 4096 * 4;
    float* logit = (float*)(wsb + off); off += (size_t)TRIP * 4;
    const size_t chunkbase = off;
    u16*   Wc1b = (u16*)(wsb + chunkbase);
    float* camp = (float*)(wsb + chunkbase + (size_t)4096 * 4096 * 2);
    const size_t phaseA = (size_t)4096 * 4096 * 2 + (size_t)4 * 192 * 4096 * 4;

    const int Rcand[6] = {18688, 14336, 9344, 4736, 2432, 1280};
    int R = 128;
    for (int c = 0; c < 6; ++c) {
        size_t chunk = (size_t)Rcand[c] * 12288;
        if (chunk < phaseA) chunk = phaseA;
        if (chunkbase + chunk <= ws_size) { R = Rcand[c]; break; }
    }
    u16* dist = (u16*)(wsb + chunkbase);
    u16* h1 = dist + (size_t)R * 4096;
    u16* h2 = dist;                       // overlays dist (dead after L1)

    hipMemsetAsync(logit, 0, (size_t)TRIP * 4, stream);
    k_cvt_all<<<(CVT_N + 255) / 256, 256, 0, stream>>>(
        Wc1, Wc1b, W1, W1b, W2, W2b, W3, W3b, f, fb);
    k_cam<<<dim3(3, 32, 4), 256, 0, stream>>>(fb, Wc1b, camp);
    k_gfin<<<768, 256, 0, stream>>>(camp, bc1, f, g);

    for (int r0 = 0; r0 < TRI; r0 += R) {
        int rows = TRIP - r0; if (rows > R) rows = R;   // mult of 128
        k_distgen<<<dim3(2, rows), 256, 0, stream>>>(g, dist, r0);
        k_gemm_relu<<<dim3(16, rows / 128), 256, 0, stream>>>(dist, W1b, b1, h1, 2048, 4096);
        k_gemm_relu<<<dim3(8,  rows / 128), 256, 0, stream>>>(h1, W2b, b2, h2, 1024, 2048);
        k_gemm3<<<dim3(4, rows / 128), 256, 0, stream>>>(h2, W3b, b3, Wsv, logit, r0);
    }
    k_sig<<<(TRI + 255) / 256, 256, 0, stream>>>(logit, bsv, out);
}